// Round 4
// baseline (18.110 us; speedup 1.0000x reference)
//
#include <hip/hip_runtime.h>

// MPA forward, M=4, F=4, V=6 — launch-latency-bound.
// Best structure (R2): 128 threads / 2 waves, single barrier, LDS only for the
// 48 A-values. This revision moves the FN/VN/m/n loads onto the SCALAR pipe
// (uniform literal indices -> s_load) so the phase-1 gather's address inputs
// arrive via a short cndmask chain instead of a dependent vector load.
//
// Algebra: 0.25*IFV / (0.25*sum) -> IFV/sum (constants cancel). Incidence of
// this graph guarantees every (fx,v) slot read in phase 3 is written in
// phase 1 (verified against the FN/VN tables), so no zero-init of sIFV.

__device__ __forceinline__ int sel4i(int x0, int x1, int x2, int x3, int j) {
    int x = x0;
    x = (j == 1) ? x1 : x;
    x = (j == 2) ? x2 : x;
    x = (j == 3) ? x3 : x;
    return x;
}

__device__ __forceinline__ int sel6i(int x0, int x1, int x2, int x3,
                                     int x4, int x5, int j) {
    int x = x0;
    x = (j == 1) ? x1 : x;
    x = (j == 2) ? x2 : x;
    x = (j == 3) ? x3 : x;
    x = (j == 4) ? x4 : x;
    x = (j == 5) ? x5 : x;
    return x;
}

__global__ __launch_bounds__(128) void mpa_kernel(
    const float* __restrict__ IVF,   // (4,4,6) = 96, a*24 + f*6 + v
    const int*   __restrict__ VN,    // (2,6)
    const int*   __restrict__ mPtr,  // scalar
    const int*   __restrict__ nPtr,  // scalar
    const int*   __restrict__ FN,    // (4,3)
    const float* __restrict__ fa,    // (4,4,4,4), f*64 + i*16 + j*4 + k
    const float* __restrict__ w0,    // (4,4,6)
    float*       __restrict__ out)   // (4,4,6)
{
    __shared__ float sIFV[96];

    const int t = threadIdx.x;

    // ---- uniform loads: scalar pipe, issue immediately -------------------
    const int mv = mPtr[0];
    const int nv = nPtr[0];
    int fn[12];
    #pragma unroll
    for (int k = 0; k < 12; ++k) fn[k] = FN[k];   // uniform -> s_load
    int vn[12];
    #pragma unroll
    for (int k = 0; k < 12; ++k) vn[k] = VN[k];   // uniform -> s_load

    // ---- per-thread identities -------------------------------------------
    const int kind = t >> 4;          // phase-1 lane role (t<48)
    const int r    = t & 15;
    const int a1   = r >> 2;
    const int f1   = r & 3;

    const int a2   = t / 24;          // phase-3 output decomposition (t<96)
    const int rem  = t - a2 * 24;
    const int f2   = rem / 6;
    const int v2   = rem - f2 * 6;

    // ---- independent vector loads (issued before phase-1 math) -----------
    float myIVF = 0.0f, myW0 = 0.0f;
    if (t < 96) {
        myIVF = IVF[t];
        myW0  = w0[t];
    }

    // ---- Phase 1: A-values, 48 threads -----------------------------------
    if (t < 48) {
        // FN row f1 via cndmask chains from scalar regs (no vector load dep)
        const int j0 = sel4i(fn[0], fn[3], fn[6], fn[9],  f1);
        const int j1 = sel4i(fn[1], fn[4], fn[7], fn[10], f1);
        const int j2 = sel4i(fn[2], fn[5], fn[8], fn[11], f1);
        const int jb = (kind == 0) ? j1 : j0;
        const int jc = (kind == 2) ? j1 : j2;

        float gb[4], gc[4];
        #pragma unroll
        for (int i = 0; i < 4; ++i) {
            gb[i] = IVF[i * 24 + f1 * 6 + jb];
            gc[i] = IVF[i * 24 + f1 * 6 + jc];
        }

        float acc = 0.0f;
        #pragma unroll
        for (int c = 0; c < 4; ++c) {
            #pragma unroll
            for (int b = 0; b < 4; ++b) {
                int faIdx;
                if (kind == 0)      faIdx = f1 * 64 + c * 16 + a1 * 4 + b; // fcab
                else if (kind == 1) faIdx = f1 * 64 + c * 16 + b * 4 + a1; // fcba
                else                faIdx = f1 * 64 + a1 * 16 + b * 4 + c; // fabc
                acc += gb[b] * gc[c] * fa[faIdx];
            }
        }

        const int jout = (kind == 0) ? j0 : ((kind == 1) ? j1 : j2);
        sIFV[a1 * 24 + f1 * 6 + jout] = acc;   // distinct v per f: no races
    }
    __syncthreads();                           // the ONLY barrier

    // ---- Phase 3: output (sum fused; 0.25 factors cancelled) -------------
    if (t < 96) {
        if (mv >= nv) {                        // uniform branch
            out[t] = myIVF;
            return;
        }
        const int va = sel6i(vn[0], vn[1], vn[2], vn[3], vn[4],  vn[5],  v2);
        const int vb = sel6i(vn[6], vn[7], vn[8], vn[9], vn[10], vn[11], v2);
        float val;
        if (f2 == va || f2 == vb) {
            const int fx   = (f2 == va) ? vb : va;
            const int base = fx * 6 + v2;
            const float x0 = sIFV[ 0 + base];
            const float x1 = sIFV[24 + base];
            const float x2 = sIFV[48 + base];
            const float x3 = sIFV[72 + base];
            const float num = sIFV[a2 * 24 + base];
            val = num / (x0 + x1 + x2 + x3);
        } else {
            val = myIVF;
        }
        out[t] = val * myW0;
    }
}

extern "C" void kernel_launch(void* const* d_in, const int* in_sizes, int n_in,
                              void* d_out, int out_size, void* d_ws, size_t ws_size,
                              hipStream_t stream) {
    (void)in_sizes; (void)n_in; (void)d_ws; (void)ws_size; (void)out_size;
    const float* IVF = (const float*)d_in[3];
    const int*   VN  = (const int*)  d_in[4];
    const int*   m   = (const int*)  d_in[5];
    const int*   n   = (const int*)  d_in[6];
    const int*   FN  = (const int*)  d_in[7];
    const float* fa  = (const float*)d_in[8];
    const float* w0  = (const float*)d_in[9];
    float*       out = (float*)d_out;

    mpa_kernel<<<1, 128, 0, stream>>>(IVF, VN, m, n, FN, fa, w0, out);
}

// Round 5
// 11.859 us; speedup vs baseline: 1.5271x; 1.5271x over previous
//
#include <hip/hip_runtime.h>

// MPA forward, M=4, F=4, V=6 — launch-latency-bound; minimize kernel critical path.
// Single block, single barrier, no LDS staging of inputs.
// [R5 = verbatim revert to the best-measured R2 kernel, 9.31 µs. R4's
//  scalar-pipe-table variant regressed to 18.1 µs.]
//
// Key simplifications vs reference:
//  * 0.25*IFV[a,fx,v] / (0.25*sum_a IFV[a,fx,v])  ->  IFV/sum (constants cancel)
//  * every (fx,v) slot read in the output phase has v in FN[fx] (variable-face
//    incidence of this MPA graph), so it is always written in phase 1 -> no
//    zero-init of the accumulator needed.
__global__ __launch_bounds__(128) void mpa_kernel(
    const float* __restrict__ IVF,   // (4,4,6) = 96, layout a*24 + f*6 + v
    const int*   __restrict__ VN,    // (2,6)
    const int*   __restrict__ mPtr,  // scalar
    const int*   __restrict__ nPtr,  // scalar
    const int*   __restrict__ FN,    // (4,3)
    const float* __restrict__ fa,    // (4,4,4,4) = 256, f*64 + i*16 + j*4 + k
    const float* __restrict__ w0,    // (4,4,6) = 96
    float*       __restrict__ out)   // (4,4,6) = 96
{
    __shared__ float sIFV[96];       // scatter target of A0/A1/A2 (48 slots live)

    const int t = threadIdx.x;

    // ---- per-thread identities -------------------------------------------
    const int kind = t >> 4;          // phase-1: 0,1,2
    const int r    = t & 15;
    const int a1   = r >> 2;
    const int f1   = r & 3;

    const int a2   = t / 24;          // phase-3
    const int rem  = t - a2 * 24;
    const int f2   = rem / 6;
    const int v2   = rem - f2 * 6;

    // ---- issue ALL independent global loads up front ---------------------
    const int mv = mPtr[0];           // uniform -> scalar loads
    const int nv = nPtr[0];

    float myIVF = 0.0f, myW0 = 0.0f;
    int va = 0, vb = 0;
    if (t < 96) {
        myIVF = IVF[t];
        myW0  = w0[t];
        va = VN[v2];                  // VN_index[0, v]
        vb = VN[6 + v2];              // VN_index[1, v]
    }

    // ---- Phase 1: A0/A1/A2, 48 threads, g gathered straight from global --
    if (t < 48) {
        const int j0 = FN[f1 * 3 + 0];
        const int j1 = FN[f1 * 3 + 1];
        const int j2 = FN[f1 * 3 + 2];
        const int jb = (kind == 0) ? j1 : j0;   // 'b'-operand column
        const int jc = (kind == 2) ? j1 : j2;   // 'c'-operand column

        float gb[4], gc[4];
        #pragma unroll
        for (int i = 0; i < 4; ++i) {
            gb[i] = IVF[i * 24 + f1 * 6 + jb];
            gc[i] = IVF[i * 24 + f1 * 6 + jc];
        }

        float acc = 0.0f;
        #pragma unroll
        for (int c = 0; c < 4; ++c) {
            #pragma unroll
            for (int b = 0; b < 4; ++b) {
                int faIdx;
                if (kind == 0)      faIdx = f1 * 64 + c * 16 + a1 * 4 + b; // fcab
                else if (kind == 1) faIdx = f1 * 64 + c * 16 + b * 4 + a1; // fcba
                else                faIdx = f1 * 64 + a1 * 16 + b * 4 + c; // fabc
                acc += gb[b] * gc[c] * fa[faIdx];
            }
        }

        const int jout = (kind == 0) ? j0 : ((kind == 1) ? j1 : j2);
        sIFV[a1 * 24 + f1 * 6 + jout] = acc;   // distinct slots per f: no races
    }
    __syncthreads();                           // the ONLY barrier

    // ---- Phase 3: output (sum fused in; 0.25 factors cancelled) ----------
    if (t < 96) {
        if (mv >= nv) {                        // uniform branch: return raw IVF
            out[t] = myIVF;
            return;
        }
        float val;
        if (f2 == va || f2 == vb) {
            const int fx   = (f2 == va) ? vb : va;
            const int base = fx * 6 + v2;
            const float x0 = sIFV[ 0 + base];
            const float x1 = sIFV[24 + base];
            const float x2 = sIFV[48 + base];
            const float x3 = sIFV[72 + base];
            const float num = sIFV[a2 * 24 + base];
            val = num / (x0 + x1 + x2 + x3);
        } else {
            val = myIVF;
        }
        out[t] = val * myW0;
    }
}

extern "C" void kernel_launch(void* const* d_in, const int* in_sizes, int n_in,
                              void* d_out, int out_size, void* d_ws, size_t ws_size,
                              hipStream_t stream) {
    (void)in_sizes; (void)n_in; (void)d_ws; (void)ws_size; (void)out_size;
    const float* IVF = (const float*)d_in[3];
    const int*   VN  = (const int*)  d_in[4];
    const int*   m   = (const int*)  d_in[5];
    const int*   n   = (const int*)  d_in[6];
    const int*   FN  = (const int*)  d_in[7];
    const float* fa  = (const float*)d_in[8];
    const float* w0  = (const float*)d_in[9];
    float*       out = (float*)d_out;

    mpa_kernel<<<1, 128, 0, stream>>>(IVF, VN, m, n, FN, fa, w0, out);
}